// Round 2
// baseline (343.452 us; speedup 1.0000x reference)
//
#include <hip/hip_runtime.h>
#include <hip/hip_bf16.h>

typedef unsigned short ushort_t;
typedef __attribute__((ext_vector_type(8))) short short8;
typedef __attribute__((ext_vector_type(4))) float floatx4;

__device__ __forceinline__ float bf2f(unsigned short u) {
    union { unsigned u; float f; } x; x.u = ((unsigned)u) << 16; return x.f;
}
__device__ __forceinline__ unsigned short f2bf(float f) {
    union { float f; unsigned u; } x; x.f = f;
    unsigned r = x.u + 0x7fffu + ((x.u >> 16) & 1u);  // RNE
    return (unsigned short)(r >> 16);
}

// ------------- convert x (f32) -> bf16 ---------------------------------------
__global__ __launch_bounds__(256) void conv_x(const float* __restrict__ x,
                                              ushort_t* __restrict__ xb, int total4) {
    int i = blockIdx.x * 256 + threadIdx.x;
    if (i < total4) {
        float4 v = *(const float4*)(x + (size_t)i * 4);
        unsigned p0 = (unsigned)f2bf(v.x) | ((unsigned)f2bf(v.y) << 16);
        unsigned p1 = (unsigned)f2bf(v.z) | ((unsigned)f2bf(v.w) << 16);
        uint2 pk; pk.x = p0; pk.y = p1;
        *(uint2*)(xb + (size_t)i * 4) = pk;
    }
}

// ------------- transpose+convert 128x128 f32 weights -> bf16 Wt[n][k] --------
__global__ __launch_bounds__(256) void transpose128(
    const float* __restrict__ Wq, const float* __restrict__ Wk,
    const float* __restrict__ Wv, const float* __restrict__ Wo,
    ushort_t* __restrict__ out)
{
    const float* W = (blockIdx.y == 0) ? Wq : (blockIdx.y == 1) ? Wk :
                     (blockIdx.y == 2) ? Wv : Wo;
    ushort_t* T = out + (size_t)blockIdx.y * 128 * 128;
    int tr = blockIdx.x >> 2, tc = blockIdx.x & 3;   // 4x4 tiles of 32x32
    __shared__ float s[32][33];
    int tx = threadIdx.x & 31, ty = threadIdx.x >> 5;  // 32 x 8
    for (int j = 0; j < 32; j += 8)
        s[ty + j][tx] = W[(tr * 32 + ty + j) * 128 + tc * 32 + tx];
    __syncthreads();
    for (int j = 0; j < 32; j += 8)
        T[(tc * 32 + ty + j) * 128 + tr * 32 + tx] = f2bf(s[tx][ty + j]);
}

// ------------- QKV fused GEMM: bf16 MFMA, f32 bias, bf16 out -----------------
__global__ __launch_bounds__(256) void gemm_qkv(
    const ushort_t* __restrict__ X, const ushort_t* __restrict__ Wt,
    const float* __restrict__ bq, const float* __restrict__ bk, const float* __restrict__ bv,
    ushort_t* __restrict__ Q, ushort_t* __restrict__ K, ushort_t* __restrict__ V, int M)
{
    __shared__ ushort_t As[64 * 136];
    __shared__ ushort_t Bs[64 * 136];
    int tid = threadIdx.x;
    int rowBase = blockIdx.x * 64;
    int wsel = blockIdx.y >> 1;
    int colBase = (blockIdx.y & 1) * 64;
    const ushort_t* Wmat = Wt + (size_t)wsel * 128 * 128;  // [n][k]
    const float* bias = (wsel == 0) ? bq : (wsel == 1) ? bk : bv;
    ushort_t* Out = (wsel == 0) ? Q : (wsel == 1) ? K : V;

    int r = tid >> 4;          // 0..15
    int c = (tid & 15) * 8;    // 0..120
    for (int rr = 0; rr < 64; rr += 16) {
        int row = rowBase + rr + r;
        int rc = (row < M) ? row : (M - 1);
        short8 v = *(const short8*)(X + (size_t)rc * 128 + c);
        *(short8*)&As[(rr + r) * 136 + c] = v;
    }
    for (int rr = 0; rr < 64; rr += 16) {
        short8 v = *(const short8*)(Wmat + (size_t)(colBase + rr + r) * 128 + c);
        *(short8*)&Bs[(rr + r) * 136 + c] = v;
    }
    __syncthreads();

    int lane = tid & 63, wave = tid >> 6;
    int wm = (wave >> 1) * 32, wn = (wave & 1) * 32;
    int l15 = lane & 15, quad = lane >> 4;
    floatx4 acc[2][2] = {};
    for (int k0 = 0; k0 < 128; k0 += 32) {
        short8 a[2], b[2];
        for (int sm = 0; sm < 2; sm++)
            a[sm] = *(const short8*)&As[(wm + sm * 16 + l15) * 136 + k0 + quad * 8];
        for (int sn = 0; sn < 2; sn++)
            b[sn] = *(const short8*)&Bs[(wn + sn * 16 + l15) * 136 + k0 + quad * 8];
        for (int sm = 0; sm < 2; sm++)
            for (int sn = 0; sn < 2; sn++)
                acc[sm][sn] = __builtin_amdgcn_mfma_f32_16x16x32_bf16(a[sm], b[sn], acc[sm][sn], 0, 0, 0);
    }
    for (int sm = 0; sm < 2; sm++)
        for (int sn = 0; sn < 2; sn++) {
            int col = colBase + wn + sn * 16 + l15;
            float bia = bias[col];
            for (int rr2 = 0; rr2 < 4; rr2++) {
                int row = rowBase + wm + sm * 16 + quad * 4 + rr2;
                if (row < M) Out[(size_t)row * 128 + col] = f2bf(acc[sm][sn][rr2] + bia);
            }
        }
}

// ---------------- CSR build ----------------
__global__ __launch_bounds__(256) void k_hist(const int* __restrict__ dst, int* __restrict__ deg, int E) {
    int i = blockIdx.x * 256 + threadIdx.x;
    if (i < E) atomicAdd(&deg[dst[i]], 1);
}

__global__ __launch_bounds__(256) void k_scan_blocks(const int* __restrict__ deg, int* __restrict__ offs,
                                                     int* __restrict__ bsums, int n) {
    __shared__ int s[256];
    int i = blockIdx.x * 256 + threadIdx.x;
    int v = (i < n) ? deg[i] : 0;
    s[threadIdx.x] = v;
    __syncthreads();
    for (int d = 1; d < 256; d <<= 1) {
        int t = (threadIdx.x >= d) ? s[threadIdx.x - d] : 0;
        __syncthreads();
        s[threadIdx.x] += t;
        __syncthreads();
    }
    int incl = s[threadIdx.x];
    if (i < n) offs[i] = incl - v;  // exclusive within block
    if (threadIdx.x == 255) bsums[blockIdx.x] = incl;
}

__global__ __launch_bounds__(256) void k_scan_sums(int* __restrict__ bs, int nb) {
    __shared__ int s[256];
    int v = (threadIdx.x < nb) ? bs[threadIdx.x] : 0;
    s[threadIdx.x] = v;
    __syncthreads();
    for (int d = 1; d < 256; d <<= 1) {
        int t = (threadIdx.x >= d) ? s[threadIdx.x - d] : 0;
        __syncthreads();
        s[threadIdx.x] += t;
        __syncthreads();
    }
    if (threadIdx.x < nb) bs[threadIdx.x] = s[threadIdx.x] - v;  // exclusive
}

__global__ __launch_bounds__(256) void k_add_base(int* __restrict__ offs, int* __restrict__ cursor,
                                                  const int* __restrict__ base, int n, int E) {
    int i = blockIdx.x * 256 + threadIdx.x;
    if (i < n) {
        int o = offs[i] + base[blockIdx.x];
        offs[i] = o;
        cursor[i] = o;
    }
    if (i == 0) offs[n] = E;
}

__global__ __launch_bounds__(256) void k_scatter(const int* __restrict__ src, const int* __restrict__ dst,
                                                 int* __restrict__ cursor, int* __restrict__ eadj, int E) {
    int i = blockIdx.x * 256 + threadIdx.x;
    if (i < E) {
        int p = atomicAdd(&cursor[dst[i]], 1);
        eadj[p] = src[i];
    }
}

// ---------------- edge attention + LN1 + LN2, one wave per dst node ----------
__global__ __launch_bounds__(256) void edge_attn(
    const ushort_t* __restrict__ Qb, const ushort_t* __restrict__ Kb, const ushort_t* __restrict__ Vb,
    const float* __restrict__ xin,
    const int* __restrict__ offs, const int* __restrict__ eadj,
    const float* __restrict__ g1, const float* __restrict__ be1,
    const float* __restrict__ g2, const float* __restrict__ be2,
    float* __restrict__ h1out, ushort_t* __restrict__ ln2out, int N)
{
    int wave = threadIdx.x >> 6, lane = threadIdx.x & 63;
    int n = blockIdx.x * 4 + wave;
    if (n >= N) return;

    unsigned qp = *(const unsigned*)(Qb + (size_t)n * 128 + lane * 2);
    float q0 = bf2f((unsigned short)(qp & 0xffff)), q1 = bf2f((unsigned short)(qp >> 16));

    int s0 = offs[n], s1 = offs[n + 1];
    float a0 = 0.f, a1 = 0.f, z = 0.f;
    for (int i = s0; i < s1; i++) {
        int sn = eadj[i];
        unsigned kp = *(const unsigned*)(Kb + (size_t)sn * 128 + lane * 2);
        unsigned vp = *(const unsigned*)(Vb + (size_t)sn * 128 + lane * 2);
        float dot = q0 * bf2f((unsigned short)(kp & 0xffff)) + q1 * bf2f((unsigned short)(kp >> 16));
        dot += __shfl_xor(dot, 1, 64);
        dot += __shfl_xor(dot, 2, 64);
        dot += __shfl_xor(dot, 4, 64);
        float sc = dot * 0.25f;
        sc = fminf(5.f, fmaxf(-5.f, sc));
        float e = expf(sc);
        a0 += e * bf2f((unsigned short)(vp & 0xffff));
        a1 += e * bf2f((unsigned short)(vp >> 16));
        z += e;
    }
    float inv = 1.f / (z + 1e-3f);

    float2 xp = *(const float2*)(xin + (size_t)n * 128 + lane * 2);
    float t0 = xp.x + a0 * inv;
    float t1 = xp.y + a1 * inv;

    // LN1 across 128 dims (wave-wide)
    float s = t0 + t1, s2 = t0 * t0 + t1 * t1;
    for (int m = 1; m < 64; m <<= 1) { s += __shfl_xor(s, m, 64); s2 += __shfl_xor(s2, m, 64); }
    float mu = s * (1.f / 128.f);
    float var = s2 * (1.f / 128.f) - mu * mu;
    float rstd = rsqrtf(var + 1e-5f);

    float2 g1p = *(const float2*)(g1 + lane * 2);
    float2 b1p = *(const float2*)(be1 + lane * 2);
    float h0 = (t0 - mu) * rstd * g1p.x + b1p.x;
    float h1v = (t1 - mu) * rstd * g1p.y + b1p.y;
    float2 hst; hst.x = h0; hst.y = h1v;
    *(float2*)(h1out + (size_t)n * 128 + lane * 2) = hst;

    // LN2
    s = h0 + h1v; s2 = h0 * h0 + h1v * h1v;
    for (int m = 1; m < 64; m <<= 1) { s += __shfl_xor(s, m, 64); s2 += __shfl_xor(s2, m, 64); }
    float mu2 = s * (1.f / 128.f);
    float var2 = s2 * (1.f / 128.f) - mu2 * mu2;
    float rstd2 = rsqrtf(var2 + 1e-5f);

    float2 g2p = *(const float2*)(g2 + lane * 2);
    float2 b2p = *(const float2*)(be2 + lane * 2);
    float l0 = (h0 - mu2) * rstd2 * g2p.x + b2p.x;
    float l1 = (h1v - mu2) * rstd2 * g2p.y + b2p.y;
    unsigned packed = (unsigned)f2bf(l0) | ((unsigned)f2bf(l1) << 16);
    *(unsigned*)(ln2out + (size_t)n * 128 + lane * 2) = packed;
}

// ---------------- output GEMM: out = h1 + relu(ln2 @ Wo + bo) -> f32 ---------
__global__ __launch_bounds__(256) void gemm_o(
    const ushort_t* __restrict__ X, const ushort_t* __restrict__ Wt,
    const float* __restrict__ bo, const float* __restrict__ h1in,
    float* __restrict__ Out, int M)
{
    __shared__ ushort_t As[64 * 136];
    __shared__ ushort_t Bs[64 * 136];
    int tid = threadIdx.x;
    int rowBase = blockIdx.x * 64;
    int colBase = blockIdx.y * 64;

    int r = tid >> 4;
    int c = (tid & 15) * 8;
    for (int rr = 0; rr < 64; rr += 16) {
        int row = rowBase + rr + r;
        int rc = (row < M) ? row : (M - 1);
        short8 v = *(const short8*)(X + (size_t)rc * 128 + c);
        *(short8*)&As[(rr + r) * 136 + c] = v;
    }
    for (int rr = 0; rr < 64; rr += 16) {
        short8 v = *(const short8*)(Wt + (size_t)(colBase + rr + r) * 128 + c);
        *(short8*)&Bs[(rr + r) * 136 + c] = v;
    }
    __syncthreads();

    int lane = tid & 63, wave = tid >> 6;
    int wm = (wave >> 1) * 32, wn = (wave & 1) * 32;
    int l15 = lane & 15, quad = lane >> 4;
    floatx4 acc[2][2] = {};
    for (int k0 = 0; k0 < 128; k0 += 32) {
        short8 a[2], b[2];
        for (int sm = 0; sm < 2; sm++)
            a[sm] = *(const short8*)&As[(wm + sm * 16 + l15) * 136 + k0 + quad * 8];
        for (int sn = 0; sn < 2; sn++)
            b[sn] = *(const short8*)&Bs[(wn + sn * 16 + l15) * 136 + k0 + quad * 8];
        for (int sm = 0; sm < 2; sm++)
            for (int sn = 0; sn < 2; sn++)
                acc[sm][sn] = __builtin_amdgcn_mfma_f32_16x16x32_bf16(a[sm], b[sn], acc[sm][sn], 0, 0, 0);
    }
    for (int sm = 0; sm < 2; sm++)
        for (int sn = 0; sn < 2; sn++) {
            int col = colBase + wn + sn * 16 + l15;
            float bia = bo[col];
            for (int rr2 = 0; rr2 < 4; rr2++) {
                int row = rowBase + wm + sm * 16 + quad * 4 + rr2;
                if (row < M) {
                    float v = acc[sm][sn][rr2] + bia;
                    v = (v > 0.f) ? v : 0.f;
                    float hv = h1in[(size_t)row * 128 + col];
                    Out[(size_t)row * 128 + col] = hv + v;
                }
            }
        }
}

extern "C" void kernel_launch(void* const* d_in, const int* in_sizes, int n_in,
                              void* d_out, int out_size, void* d_ws, size_t ws_size,
                              hipStream_t stream) {
    const int D = 128;
    const int N = in_sizes[0] / D;
    const int E = in_sizes[1];

    const float* x   = (const float*)d_in[0];
    const int*   src = (const int*)d_in[1];
    const int*   dst = (const int*)d_in[2];
    const float* Wq  = (const float*)d_in[3];
    const float* bq  = (const float*)d_in[4];
    const float* Wk  = (const float*)d_in[5];
    const float* bk  = (const float*)d_in[6];
    const float* Wv  = (const float*)d_in[7];
    const float* bv  = (const float*)d_in[8];
    const float* Wo  = (const float*)d_in[9];
    const float* bo  = (const float*)d_in[10];
    const float* g1  = (const float*)d_in[11];
    const float* be1 = (const float*)d_in[12];
    const float* g2  = (const float*)d_in[13];
    const float* be2 = (const float*)d_in[14];

    char* ws = (char*)d_ws;
    size_t o = 0;
    auto alloc = [&](size_t b) { o = (o + 255) & ~(size_t)255; size_t r = o; o += b; return r; };
    ushort_t* xb   = (ushort_t*)(ws + alloc((size_t)N * D * 2));
    ushort_t* Qb   = (ushort_t*)(ws + alloc((size_t)N * D * 2));
    ushort_t* Kb   = (ushort_t*)(ws + alloc((size_t)N * D * 2));
    ushort_t* Vb   = (ushort_t*)(ws + alloc((size_t)N * D * 2));
    ushort_t* ln2  = (ushort_t*)(ws + alloc((size_t)N * D * 2));
    float*    h1   = (float*)(ws + alloc((size_t)N * D * 4));
    ushort_t* Wt   = (ushort_t*)(ws + alloc((size_t)4 * 128 * 128 * 2));
    int*      deg  = (int*)(ws + alloc((size_t)N * 4));
    int*      offs = (int*)(ws + alloc((size_t)(N + 1) * 4));
    int*      cur  = (int*)(ws + alloc((size_t)N * 4));
    int*      bsum = (int*)(ws + alloc((size_t)256 * 4));
    int*      eadj = (int*)(ws + alloc((size_t)E * 4));

    int nScanBlocks = (N + 255) / 256;
    int nEdgeBlocks = (E + 255) / 256;
    int nRowTiles = (N + 63) / 64;
    int total4 = (N * D) / 4;

    hipMemsetAsync(deg, 0, (size_t)N * 4, stream);
    conv_x<<<(total4 + 255) / 256, 256, 0, stream>>>(x, xb, total4);
    transpose128<<<dim3(16, 4), 256, 0, stream>>>(Wq, Wk, Wv, Wo, Wt);
    gemm_qkv<<<dim3(nRowTiles, 6), 256, 0, stream>>>(xb, Wt, bq, bk, bv, Qb, Kb, Vb, N);
    k_hist<<<nEdgeBlocks, 256, 0, stream>>>(dst, deg, E);
    k_scan_blocks<<<nScanBlocks, 256, 0, stream>>>(deg, offs, bsum, N);
    k_scan_sums<<<1, 256, 0, stream>>>(bsum, nScanBlocks);
    k_add_base<<<nScanBlocks, 256, 0, stream>>>(offs, cur, bsum, N, E);
    k_scatter<<<nEdgeBlocks, 256, 0, stream>>>(src, dst, cur, eadj, E);
    edge_attn<<<(N + 3) / 4, 256, 0, stream>>>(Qb, Kb, Vb, x, offs, eadj, g1, be1, g2, be2, h1, ln2, N);
    gemm_o<<<dim3(nRowTiles, 2), 256, 0, stream>>>(ln2, Wt + 3 * 128 * 128, bo, h1, (float*)d_out, N);
}

// Round 3
// 336.681 us; speedup vs baseline: 1.0201x; 1.0201x over previous
//
#include <hip/hip_runtime.h>
#include <hip/hip_bf16.h>

typedef unsigned short ushort_t;
typedef __attribute__((ext_vector_type(8))) short short8;
typedef __attribute__((ext_vector_type(4))) float floatx4;

__device__ __forceinline__ float bf2f(unsigned short u) {
    union { unsigned u; float f; } x; x.u = ((unsigned)u) << 16; return x.f;
}
__device__ __forceinline__ unsigned short f2bf(float f) {
    union { float f; unsigned u; } x; x.f = f;
    unsigned r = x.u + 0x7fffu + ((x.u >> 16) & 1u);  // RNE
    return (unsigned short)(r >> 16);
}
__device__ __forceinline__ float u2f(unsigned u) {
    union { unsigned u; float f; } x; x.u = u; return x.f;
}

// ------------- transpose+convert 128x128 f32 weights -> bf16 Wt[n][k] --------
__global__ __launch_bounds__(256) void transpose128(
    const float* __restrict__ Wq, const float* __restrict__ Wk,
    const float* __restrict__ Wv, const float* __restrict__ Wo,
    ushort_t* __restrict__ out)
{
    const float* W = (blockIdx.y == 0) ? Wq : (blockIdx.y == 1) ? Wk :
                     (blockIdx.y == 2) ? Wv : Wo;
    ushort_t* T = out + (size_t)blockIdx.y * 128 * 128;
    int tr = blockIdx.x >> 2, tc = blockIdx.x & 3;   // 4x4 tiles of 32x32
    __shared__ float s[32][33];
    int tx = threadIdx.x & 31, ty = threadIdx.x >> 5;  // 32 x 8
    for (int j = 0; j < 32; j += 8)
        s[ty + j][tx] = W[(tr * 32 + ty + j) * 128 + tc * 32 + tx];
    __syncthreads();
    for (int j = 0; j < 32; j += 8)
        T[(tc * 32 + ty + j) * 128 + tr * 32 + tx] = f2bf(s[tx][ty + j]);
}

// ------------- fused convert + QKV GEMM --------------------------------------
// X f32 [M,128] staged once as bf16; 3 weights; Q -> [M,128] bf16,
// K/V -> interleaved KV[M][256]: ushorts [4t..4t+3] = K[2t],K[2t+1],V[2t],V[2t+1]
__global__ __launch_bounds__(256) void gemm_qkvx(
    const float* __restrict__ X, const ushort_t* __restrict__ Wt,
    const float* __restrict__ bq, const float* __restrict__ bk, const float* __restrict__ bv,
    ushort_t* __restrict__ Q, ushort_t* __restrict__ KV, int M)
{
    __shared__ ushort_t Xs[64 * 136];
    __shared__ ushort_t Ws[128 * 136];
    int tid = threadIdx.x;
    int rowBase = blockIdx.x * 64;
    int r = tid >> 4;            // 0..15
    int c = (tid & 15) * 8;      // 0..120

    // stage X tile (64x128), f32 -> bf16
    for (int rr = 0; rr < 64; rr += 16) {
        int row = rowBase + rr + r;
        int rc = (row < M) ? row : (M - 1);
        float4 f0 = *(const float4*)(X + (size_t)rc * 128 + c);
        float4 f1 = *(const float4*)(X + (size_t)rc * 128 + c + 4);
        short8 v;
        v[0] = (short)f2bf(f0.x); v[1] = (short)f2bf(f0.y);
        v[2] = (short)f2bf(f0.z); v[3] = (short)f2bf(f0.w);
        v[4] = (short)f2bf(f1.x); v[5] = (short)f2bf(f1.y);
        v[6] = (short)f2bf(f1.z); v[7] = (short)f2bf(f1.w);
        *(short8*)&Xs[(rr + r) * 136 + c] = v;
    }

    int lane = tid & 63, wave = tid >> 6;
    int wm = wave * 16;
    int l15 = lane & 15, quad = lane >> 4;

    for (int w = 0; w < 3; w++) {
        const ushort_t* Wm = Wt + (size_t)w * 16384;  // [n][k]
        __syncthreads();
        for (int rr = 0; rr < 128; rr += 16) {
            short8 v = *(const short8*)(Wm + (size_t)(rr + r) * 128 + c);
            *(short8*)&Ws[(rr + r) * 136 + c] = v;
        }
        __syncthreads();

        floatx4 acc[8] = {};
        for (int k0 = 0; k0 < 128; k0 += 32) {
            short8 a = *(const short8*)&Xs[(wm + l15) * 136 + k0 + quad * 8];
            short8 b[8];
            for (int sn = 0; sn < 8; sn++)
                b[sn] = *(const short8*)&Ws[(sn * 16 + l15) * 136 + k0 + quad * 8];
            for (int sn = 0; sn < 8; sn++)
                acc[sn] = __builtin_amdgcn_mfma_f32_16x16x32_bf16(a, b[sn], acc[sn], 0, 0, 0);
        }

        const float* bias = (w == 0) ? bq : (w == 1) ? bk : bv;
        for (int sn = 0; sn < 8; sn++) {
            int col = sn * 16 + l15;
            float bia = bias[col];
            for (int rr2 = 0; rr2 < 4; rr2++) {
                int row = rowBase + wm + quad * 4 + rr2;
                if (row < M) {
                    ushort_t val = f2bf(acc[sn][rr2] + bia);
                    if (w == 0) {
                        Q[(size_t)row * 128 + col] = val;
                    } else {
                        size_t idx = (size_t)row * 256 + ((col >> 1) << 2) + (col & 1) + ((w == 2) ? 2 : 0);
                        KV[idx] = val;
                    }
                }
            }
        }
    }
}

// ---------------- CSR build ----------------
__global__ __launch_bounds__(256) void k_hist(const int* __restrict__ dst, int* __restrict__ deg, int E) {
    int i = blockIdx.x * 256 + threadIdx.x;
    if (i < E) atomicAdd(&deg[dst[i]], 1);
}

__global__ __launch_bounds__(256) void k_scan_blocks(const int* __restrict__ deg, int* __restrict__ offs,
                                                     int* __restrict__ bsums, int n) {
    __shared__ int s[256];
    int i = blockIdx.x * 256 + threadIdx.x;
    int v = (i < n) ? deg[i] : 0;
    s[threadIdx.x] = v;
    __syncthreads();
    for (int d = 1; d < 256; d <<= 1) {
        int t = (threadIdx.x >= d) ? s[threadIdx.x - d] : 0;
        __syncthreads();
        s[threadIdx.x] += t;
        __syncthreads();
    }
    int incl = s[threadIdx.x];
    if (i < n) offs[i] = incl - v;  // exclusive within block
    if (threadIdx.x == 255) bsums[blockIdx.x] = incl;
}

__global__ __launch_bounds__(256) void k_scan_sums(int* __restrict__ bs, int nb) {
    __shared__ int s[256];
    int v = (threadIdx.x < nb) ? bs[threadIdx.x] : 0;
    s[threadIdx.x] = v;
    __syncthreads();
    for (int d = 1; d < 256; d <<= 1) {
        int t = (threadIdx.x >= d) ? s[threadIdx.x - d] : 0;
        __syncthreads();
        s[threadIdx.x] += t;
        __syncthreads();
    }
    if (threadIdx.x < nb) bs[threadIdx.x] = s[threadIdx.x] - v;  // exclusive
}

__global__ __launch_bounds__(256) void k_add_base(int* __restrict__ offs, int* __restrict__ cursor,
                                                  const int* __restrict__ base, int n, int E) {
    int i = blockIdx.x * 256 + threadIdx.x;
    if (i < n) {
        int o = offs[i] + base[blockIdx.x];
        offs[i] = o;
        cursor[i] = o;
    }
    if (i == 0) offs[n] = E;
}

__global__ __launch_bounds__(256) void k_scatter(const int* __restrict__ src, const int* __restrict__ dst,
                                                 int* __restrict__ cursor, int* __restrict__ eadj, int E) {
    int i = blockIdx.x * 256 + threadIdx.x;
    if (i < E) {
        int p = atomicAdd(&cursor[dst[i]], 1);
        eadj[p] = src[i];
    }
}

// ---------------- edge attention + LN1 + LN2, one wave per dst node ----------
__global__ __launch_bounds__(256) void edge_attn(
    const ushort_t* __restrict__ Qb, const ushort_t* __restrict__ KV,
    const float* __restrict__ xin,
    const int* __restrict__ offs, const int* __restrict__ eadj,
    const float* __restrict__ g1, const float* __restrict__ be1,
    const float* __restrict__ g2, const float* __restrict__ be2,
    float* __restrict__ h1out, ushort_t* __restrict__ ln2out, int N)
{
    int wave = threadIdx.x >> 6, lane = threadIdx.x & 63;
    int n = blockIdx.x * 4 + wave;
    if (n >= N) return;

    unsigned qp = *(const unsigned*)(Qb + (size_t)n * 128 + lane * 2);
    float q1 = u2f(qp & 0xffff0000u);
    float q0 = u2f(qp << 16);

    int s0 = offs[n], s1 = offs[n + 1];
    float a0 = 0.f, a1 = 0.f, z = 0.f;
    for (int base = s0; base < s1; base += 64) {
        int cnt = min(s1 - base, 64);
        int ee = (base + lane < s1) ? eadj[base + lane] : 0;
        #pragma unroll 4
        for (int j = 0; j < cnt; j++) {
            int sn = __shfl(ee, j, 64);
            uint2 kv = *(const uint2*)(KV + (size_t)sn * 256 + lane * 4);
            float kh = u2f(kv.x & 0xffff0000u);
            float kl = u2f(kv.x << 16);
            float d = q0 * kl + q1 * kh;
            d += __shfl_xor(d, 1, 64);
            d += __shfl_xor(d, 2, 64);
            d += __shfl_xor(d, 4, 64);
            float sc = fminf(5.f, fmaxf(-5.f, d * 0.25f));
            float e = __expf(sc);
            float vh = u2f(kv.y & 0xffff0000u);
            float vl = u2f(kv.y << 16);
            a0 = fmaf(e, vl, a0);
            a1 = fmaf(e, vh, a1);
            z += e;
        }
    }
    float inv = 1.f / (z + 1e-3f);

    float2 xp = *(const float2*)(xin + (size_t)n * 128 + lane * 2);
    float t0 = xp.x + a0 * inv;
    float t1 = xp.y + a1 * inv;

    // LN1 across 128 dims (wave-wide)
    float s = t0 + t1, s2 = t0 * t0 + t1 * t1;
    for (int m = 1; m < 64; m <<= 1) { s += __shfl_xor(s, m, 64); s2 += __shfl_xor(s2, m, 64); }
    float mu = s * (1.f / 128.f);
    float var = s2 * (1.f / 128.f) - mu * mu;
    float rstd = rsqrtf(var + 1e-5f);

    float2 g1p = *(const float2*)(g1 + lane * 2);
    float2 b1p = *(const float2*)(be1 + lane * 2);
    float h0 = (t0 - mu) * rstd * g1p.x + b1p.x;
    float h1v = (t1 - mu) * rstd * g1p.y + b1p.y;
    float2 hst; hst.x = h0; hst.y = h1v;
    *(float2*)(h1out + (size_t)n * 128 + lane * 2) = hst;

    // LN2
    s = h0 + h1v; s2 = h0 * h0 + h1v * h1v;
    for (int m = 1; m < 64; m <<= 1) { s += __shfl_xor(s, m, 64); s2 += __shfl_xor(s2, m, 64); }
    float mu2 = s * (1.f / 128.f);
    float var2 = s2 * (1.f / 128.f) - mu2 * mu2;
    float rstd2 = rsqrtf(var2 + 1e-5f);

    float2 g2p = *(const float2*)(g2 + lane * 2);
    float2 b2p = *(const float2*)(be2 + lane * 2);
    float l0 = (h0 - mu2) * rstd2 * g2p.x + b2p.x;
    float l1 = (h1v - mu2) * rstd2 * g2p.y + b2p.y;
    unsigned packed = (unsigned)f2bf(l0) | ((unsigned)f2bf(l1) << 16);
    *(unsigned*)(ln2out + (size_t)n * 128 + lane * 2) = packed;
}

// ---------------- output GEMM: out = h1 + relu(ln2 @ Wo + bo) -> f32 ---------
__global__ __launch_bounds__(256) void gemm_o(
    const ushort_t* __restrict__ X, const ushort_t* __restrict__ Wt,
    const float* __restrict__ bo, const float* __restrict__ h1in,
    float* __restrict__ Out, int M)
{
    __shared__ ushort_t Xs[64 * 136];
    __shared__ ushort_t Ws[128 * 136];
    int tid = threadIdx.x;
    int rowBase = blockIdx.x * 64;
    int r = tid >> 4;
    int c = (tid & 15) * 8;

    for (int rr = 0; rr < 64; rr += 16) {
        int row = rowBase + rr + r;
        int rc = (row < M) ? row : (M - 1);
        short8 v = *(const short8*)(X + (size_t)rc * 128 + c);
        *(short8*)&Xs[(rr + r) * 136 + c] = v;
    }
    for (int rr = 0; rr < 128; rr += 16) {
        short8 v = *(const short8*)(Wt + (size_t)(rr + r) * 128 + c);
        *(short8*)&Ws[(rr + r) * 136 + c] = v;
    }
    __syncthreads();

    int lane = tid & 63, wave = tid >> 6;
    int wm = wave * 16;
    int l15 = lane & 15, quad = lane >> 4;
    floatx4 acc[8] = {};
    for (int k0 = 0; k0 < 128; k0 += 32) {
        short8 a = *(const short8*)&Xs[(wm + l15) * 136 + k0 + quad * 8];
        short8 b[8];
        for (int sn = 0; sn < 8; sn++)
            b[sn] = *(const short8*)&Ws[(sn * 16 + l15) * 136 + k0 + quad * 8];
        for (int sn = 0; sn < 8; sn++)
            acc[sn] = __builtin_amdgcn_mfma_f32_16x16x32_bf16(a, b[sn], acc[sn], 0, 0, 0);
    }
    for (int sn = 0; sn < 8; sn++) {
        int col = sn * 16 + l15;
        float bia = bo[col];
        for (int rr2 = 0; rr2 < 4; rr2++) {
            int row = rowBase + wm + quad * 4 + rr2;
            if (row < M) {
                float v = acc[sn][rr2] + bia;
                v = fmaxf(v, 0.f);
                float hv = h1in[(size_t)row * 128 + col];
                Out[(size_t)row * 128 + col] = hv + v;
            }
        }
    }
}

extern "C" void kernel_launch(void* const* d_in, const int* in_sizes, int n_in,
                              void* d_out, int out_size, void* d_ws, size_t ws_size,
                              hipStream_t stream) {
    const int D = 128;
    const int N = in_sizes[0] / D;
    const int E = in_sizes[1];

    const float* x   = (const float*)d_in[0];
    const int*   src = (const int*)d_in[1];
    const int*   dst = (const int*)d_in[2];
    const float* Wq  = (const float*)d_in[3];
    const float* bq  = (const float*)d_in[4];
    const float* Wk  = (const float*)d_in[5];
    const float* bk  = (const float*)d_in[6];
    const float* Wv  = (const float*)d_in[7];
    const float* bv  = (const float*)d_in[8];
    const float* Wo  = (const float*)d_in[9];
    const float* bo  = (const float*)d_in[10];
    const float* g1  = (const float*)d_in[11];
    const float* be1 = (const float*)d_in[12];
    const float* g2  = (const float*)d_in[13];
    const float* be2 = (const float*)d_in[14];

    char* ws = (char*)d_ws;
    size_t o = 0;
    auto alloc = [&](size_t b) { o = (o + 255) & ~(size_t)255; size_t r = o; o += b; return r; };
    ushort_t* Qb   = (ushort_t*)(ws + alloc((size_t)N * D * 2));
    ushort_t* KVb  = (ushort_t*)(ws + alloc((size_t)N * D * 4));   // interleaved K,V
    ushort_t* ln2  = (ushort_t*)(ws + alloc((size_t)N * D * 2));
    float*    h1   = (float*)(ws + alloc((size_t)N * D * 4));
    ushort_t* Wt   = (ushort_t*)(ws + alloc((size_t)4 * 128 * 128 * 2));
    int*      deg  = (int*)(ws + alloc((size_t)N * 4));
    int*      offs = (int*)(ws + alloc((size_t)(N + 1) * 4));
    int*      cur  = (int*)(ws + alloc((size_t)N * 4));
    int*      bsum = (int*)(ws + alloc((size_t)256 * 4));
    int*      eadj = (int*)(ws + alloc((size_t)E * 4));

    int nScanBlocks = (N + 255) / 256;
    int nEdgeBlocks = (E + 255) / 256;
    int nRowTiles = (N + 63) / 64;

    hipMemsetAsync(deg, 0, (size_t)N * 4, stream);
    transpose128<<<dim3(16, 4), 256, 0, stream>>>(Wq, Wk, Wv, Wo, Wt);
    gemm_qkvx<<<nRowTiles, 256, 0, stream>>>(x, Wt, bq, bk, bv, Qb, KVb, N);
    k_hist<<<nEdgeBlocks, 256, 0, stream>>>(dst, deg, E);
    k_scan_blocks<<<nScanBlocks, 256, 0, stream>>>(deg, offs, bsum, N);
    k_scan_sums<<<1, 256, 0, stream>>>(bsum, nScanBlocks);
    k_add_base<<<nScanBlocks, 256, 0, stream>>>(offs, cur, bsum, N, E);
    k_scatter<<<nEdgeBlocks, 256, 0, stream>>>(src, dst, cur, eadj, E);
    edge_attn<<<(N + 3) / 4, 256, 0, stream>>>(Qb, KVb, x, offs, eadj, g1, be1, g2, be2, h1, ln2, N);
    gemm_o<<<nRowTiles, 256, 0, stream>>>(ln2, Wt + 3 * 128 * 128, bo, h1, (float*)d_out, N);
}